// Round 4
// baseline (334.077 us; speedup 1.0000x reference)
//
#include <hip/hip_runtime.h>

using u16 = unsigned short;
using f32x4 = __attribute__((ext_vector_type(4))) float;
using s16x8 = __attribute__((ext_vector_type(8))) short;
using u16x4 = __attribute__((ext_vector_type(4))) unsigned short;

__device__ __forceinline__ u16 f2bf(float f) {
  unsigned u = __float_as_uint(f);
  return (u16)((u + 0x7FFFu + ((u >> 16) & 1u)) >> 16);
}

__device__ __forceinline__ f32x4 mfma16(s16x8 a, s16x8 b, f32x4 c) {
  return __builtin_amdgcn_mfma_f32_16x16x32_bf16(a, b, c, 0, 0, 0);
}

__device__ __forceinline__ void gld16(const void* g, void* l) {
  __builtin_amdgcn_global_load_lds(
      (const __attribute__((address_space(1))) unsigned int*)g,
      (__attribute__((address_space(3))) unsigned int*)l, 16, 0, 0);
}

// ---------------- elementwise casts ----------------
__global__ __launch_bounds__(256) void cast_bf16(const float* __restrict__ in,
                                                 u16* __restrict__ out, int n4) {
  int i = blockIdx.x * 256 + threadIdx.x;
  if (i >= n4) return;
  f32x4 v = *(const f32x4*)(in + (size_t)i * 4);
  u16x4 o = {f2bf(v[0]), f2bf(v[1]), f2bf(v[2]), f2bf(v[3])};
  *(u16x4*)(out + (size_t)i * 4) = o;
}

// in: (R, C) f32 row-major  ->  out: (C, R) bf16 row-major
__global__ __launch_bounds__(256) void transpose_cast(const float* __restrict__ in,
                                                      u16* __restrict__ out,
                                                      int R, int C) {
  __shared__ float t[32][33];
  int bx = blockIdx.x, by = blockIdx.y;
  int tx = threadIdx.x & 31, ty = threadIdx.x >> 5;  // ty 0..7
#pragma unroll
  for (int r = 0; r < 4; r++) {
    int row = by * 32 + ty + r * 8;
    t[ty + r * 8][tx] = in[(size_t)row * C + bx * 32 + tx];
  }
  __syncthreads();
#pragma unroll
  for (int r = 0; r < 4; r++) {
    int orow = bx * 32 + ty + r * 8;
    out[(size_t)orow * R + by * 32 + tx] = f2bf(t[tx][ty + r * 8]);
  }
}

// ---------------- GEMM mainloop (A: MxK bf16, Bt: NxK bf16) ----------------
__device__ __forceinline__ void gemm_mainloop(const u16* A, const u16* Bt, int K,
                                              u16* As, u16* Bs, f32x4 acc[4][4]) {
  const int tid = threadIdx.x;
  const int row = tid >> 2, c16 = tid & 3;
  const int lane = tid & 63, wid = tid >> 6;
  const int wm = wid >> 1, wn = wid & 1, lg = lane >> 4, lr = lane & 15;
  const u16* ga = A + (size_t)row * K + c16 * 8;
  const u16* gb = Bt + (size_t)row * K + c16 * 8;
  const size_t rowskip = (size_t)64 * K;
  for (int k0 = 0; k0 < K; k0 += 32) {
    gld16(ga + k0, As + tid * 8);
    gld16(ga + rowskip + k0, As + 2048 + tid * 8);
    gld16(gb + k0, Bs + tid * 8);
    gld16(gb + rowskip + k0, Bs + 2048 + tid * 8);
    __syncthreads();
    s16x8 af[4], bfr[4];
#pragma unroll
    for (int i = 0; i < 4; i++)
      af[i] = *(const s16x8*)(As + (wm * 64 + i * 16 + lr) * 32 + lg * 8);
#pragma unroll
    for (int j = 0; j < 4; j++)
      bfr[j] = *(const s16x8*)(Bs + (wn * 64 + j * 16 + lr) * 32 + lg * 8);
#pragma unroll
    for (int i = 0; i < 4; i++)
#pragma unroll
      for (int j = 0; j < 4; j++) acc[i][j] = mfma16(af[i], bfr[j], acc[i][j]);
    __syncthreads();
  }
}

// QKV GEMM: x_bf (4096x1024) @ attn_wT (3072x1024)^T + bias -> scatter q,k,kT,vT (bf16)
__global__ __launch_bounds__(256) void gemm_qkv(const u16* __restrict__ A,
                                                const u16* __restrict__ Bt,
                                                const float* __restrict__ bias,
                                                u16* __restrict__ qo, u16* __restrict__ ko,
                                                u16* __restrict__ kTo, u16* __restrict__ vTo) {
  __shared__ u16 As[4096];
  __shared__ u16 Bs[4096];
  int m0 = blockIdx.x * 128, n0 = blockIdx.y * 128;
  f32x4 acc[4][4] = {};
  gemm_mainloop(A + (size_t)m0 * 1024, Bt + (size_t)n0 * 1024, 1024, As, Bs, acc);
  int lane = threadIdx.x & 63, wid = threadIdx.x >> 6;
  int wm = wid >> 1, wn = wid & 1, lg = lane >> 4, lr = lane & 15;
#pragma unroll
  for (int i = 0; i < 4; i++) {
    int mb = m0 + wm * 64 + i * 16 + lg * 4;
    int b = mb >> 10, tb = mb & 1023;
#pragma unroll
    for (int j = 0; j < 4; j++) {
      int n = n0 + wn * 64 + j * 16 + lr;
      float bs = bias[n];
      int sel = n >> 10, hd = n & 1023, h = hd >> 6, d = hd & 63;
      int bh = b * 16 + h;
      u16 u0 = f2bf(acc[i][j][0] + bs), u1 = f2bf(acc[i][j][1] + bs);
      u16 u2 = f2bf(acc[i][j][2] + bs), u3 = f2bf(acc[i][j][3] + bs);
      if (sel == 0) {
        u16* qp = qo + ((size_t)bh << 16) + ((size_t)tb << 6) + d;
        qp[0] = u0; qp[64] = u1; qp[128] = u2; qp[192] = u3;
      } else if (sel == 1) {
        u16* kp = ko + ((size_t)bh << 16) + ((size_t)tb << 6) + d;
        kp[0] = u0; kp[64] = u1; kp[128] = u2; kp[192] = u3;
        u16x4 pk = {u0, u1, u2, u3};
        *(u16x4*)(kTo + ((size_t)(bh * 64 + d) << 10) + tb) = pk;
      } else {
        u16x4 pk = {u0, u1, u2, u3};
        *(u16x4*)(vTo + ((size_t)(bh * 64 + d) << 10) + tb) = pk;
      }
    }
  }
}

// proj GEMM: combined (4096x1024) @ proj_wT (1024x1024)^T + bias -> f32 out
__global__ __launch_bounds__(256) void gemm_proj(const u16* __restrict__ A,
                                                 const u16* __restrict__ Bt,
                                                 const float* __restrict__ bias,
                                                 float* __restrict__ out) {
  __shared__ u16 As[4096];
  __shared__ u16 Bs[4096];
  int m0 = blockIdx.x * 128, n0 = blockIdx.y * 128;
  f32x4 acc[4][4] = {};
  gemm_mainloop(A + (size_t)m0 * 1024, Bt + (size_t)n0 * 1024, 1024, As, Bs, acc);
  int lane = threadIdx.x & 63, wid = threadIdx.x >> 6;
  int wm = wid >> 1, wn = wid & 1, lg = lane >> 4, lr = lane & 15;
#pragma unroll
  for (int i = 0; i < 4; i++) {
    int mb = m0 + wm * 64 + i * 16 + lg * 4;
#pragma unroll
    for (int j = 0; j < 4; j++) {
      int n = n0 + wn * 64 + j * 16 + lr;
      float bs = bias[n];
#pragma unroll
      for (int r = 0; r < 4; r++)
        out[(size_t)(mb + r) * 1024 + n] = acc[i][j][r] + bs;
    }
  }
}

// ---------------- conv compression (+bias,+LN,+GeLU) ----------------
__global__ __launch_bounds__(256) void conv_comp(const u16* __restrict__ kT,
                                                 const u16* __restrict__ vT,
                                                 const u16* __restrict__ cw,
                                                 const float* __restrict__ cb,
                                                 const float* __restrict__ lnw,
                                                 const float* __restrict__ lnb,
                                                 u16* __restrict__ kcomp,
                                                 u16* __restrict__ vcompT) {
  int bh = blockIdx.x, sel = blockIdx.y;
  const u16* src = (sel ? vT : kT) + ((size_t)bh << 16);
  int tid = threadIdx.x, wid = tid >> 6, lane = tid & 63, lg = lane >> 4, lr = lane & 15;
  f32x4 acc[4] = {};
  int arow = wid * 16 + lr;
  if (arow > 62) arow = 62;  // op=63 masked; avoid OOB window
  const u16* abase = src + (size_t)arow * 16 + lg * 8;
#pragma unroll 4
  for (int ic = 0; ic < 64; ic++) {
    s16x8 a = *(const s16x8*)(abase + ic * 1024);
#pragma unroll
    for (int j = 0; j < 4; j++) {
      s16x8 bfr = *(const s16x8*)(cw + (size_t)(j * 16 + lr) * 2048 + ic * 32 + lg * 8);
      acc[j] = mfma16(a, bfr, acc[j]);
    }
  }
  float lwv[4], lbv[4];
#pragma unroll
  for (int j = 0; j < 4; j++) {
    int oc = j * 16 + lr;
    float cbv = cb[oc];
    acc[j][0] += cbv; acc[j][1] += cbv; acc[j][2] += cbv; acc[j][3] += cbv;
    lwv[j] = lnw[oc]; lbv[j] = lnb[oc];
  }
#pragma unroll
  for (int r = 0; r < 4; r++) {
    float s = acc[0][r] + acc[1][r] + acc[2][r] + acc[3][r];
    float q = acc[0][r] * acc[0][r] + acc[1][r] * acc[1][r] +
              acc[2][r] * acc[2][r] + acc[3][r] * acc[3][r];
#pragma unroll
    for (int off = 1; off < 16; off <<= 1) {
      s += __shfl_xor(s, off);
      q += __shfl_xor(q, off);
    }
    float mean = s * (1.f / 64.f);
    float var = q * (1.f / 64.f) - mean * mean;
    float rstd = rsqrtf(fmaxf(var, 0.f) + 1e-5f);
    int op = wid * 16 + lg * 4 + r;
#pragma unroll
    for (int j = 0; j < 4; j++) {
      float y = (acc[j][r] - mean) * rstd * lwv[j] + lbv[j];
      y = 0.5f * y * (1.0f + erff(y * 0.70710678118f));
      if (op > 62) y = 0.f;
      int oc = j * 16 + lr;
      if (sel == 0) kcomp[((size_t)bh << 12) + (op << 6) + oc] = f2bf(y);
      else          vcompT[((size_t)bh << 12) + (oc << 6) + op] = f2bf(y);
    }
  }
}

// ---------------- flash attention v3: barrier-free, K/V direct from L2 ----------------
// 4 waves/block, 64 q-rows/block; K/V fragments read straight from global (L2-resident
// via XCD-pinned bh); LDS holds only the per-wave P roundtrip (9 KB/block).
// Swapped QK^T (mfma(K,Q)); PV as O^T = V^T * P^T. exp2-domain softmax.
__global__ __launch_bounds__(256) void flash64(const u16* __restrict__ qg,
                                               const u16* __restrict__ kg,
                                               const u16* __restrict__ vg,
                                               float* __restrict__ outg,
                                               int k_bh, int v_bh, int vrow, int kvmax) {
  __shared__ u16 Pl[4][1152];  // per-wave P: 16 q-rows x 72 u16 (144B stride)
  const int tid = threadIdx.x;
  const int w = tid >> 6, lane = tid & 63, lg = lane >> 4, lr = lane & 15;
  // XCD-aware decode: idx = qrank*64 + (bh&7)*8 + xcd ; bh = xcd*8 + (j&7).
  // All 16 q-tiles of a bh (and 8 bh) pin to one XCD's L2; heavy q-tiles first.
  const int idx = blockIdx.x;
  const int nqt = gridDim.x >> 6;
  const int xcd = idx & 7, j = idx >> 3;
  const int bh = xcd * 8 + (j & 7);
  const int qt0 = nqt - 1 - (j >> 3);
  const int q0 = qt0 * 64;
  const int qrow = q0 + w * 16 + lr;
  const u16* qb = qg + ((size_t)bh << 16) + (size_t)qrow * 64 + lg * 8;
  s16x8 qf0 = *(const s16x8*)(qb);
  s16x8 qf1 = *(const s16x8*)(qb + 32);
  const u16* kb = kg + (size_t)bh * k_bh;
  const u16* vb = vg + (size_t)bh * v_bh;
  int nt = qt0 + 1;
  int ntk = (kvmax + 63) >> 6;
  if (nt > ntk) nt = ntk;
  u16* Pw = Pl[w];
  f32x4 ot[4] = {};
  float m = -INFINITY, l = 0.f;
  const float SCL = 0.125f * 1.44269504089f;  // fold log2e: softmax in exp2 domain
  for (int t = 0; t < nt; t++) {
    const int kv0 = t * 64;
    const bool full = (kv0 + 63 <= q0 + w * 16) && (kv0 + 64 <= kvmax);
    // ---- QK^T: S^T[kv 64][q 16], K fragments direct from global ----
    f32x4 st[4];
    __builtin_amdgcn_s_setprio(1);
#pragma unroll
    for (int kvt = 0; kvt < 4; kvt++) {
      const u16* ka = kb + (size_t)(kv0 + kvt * 16 + lr) * 64 + lg * 8;
      f32x4 z = {};
      z = mfma16(*(const s16x8*)(ka), qf0, z);
      z = mfma16(*(const s16x8*)(ka + 32), qf1, z);
      st[kvt] = z;
    }
    __builtin_amdgcn_s_setprio(0);
    // ---- online softmax (lane holds 16 P-values for q=qrow) ----
    float p[16];
    float tm = -INFINITY;
    if (full) {
#pragma unroll
      for (int kvt = 0; kvt < 4; kvt++)
#pragma unroll
        for (int r = 0; r < 4; r++) {
          float v = st[kvt][r] * SCL;
          p[kvt * 4 + r] = v;
          tm = fmaxf(tm, v);
        }
    } else {
#pragma unroll
      for (int kvt = 0; kvt < 4; kvt++)
#pragma unroll
        for (int r = 0; r < 4; r++) {
          int kvi = kv0 + kvt * 16 + lg * 4 + r;
          float v = st[kvt][r] * SCL;
          v = (kvi <= qrow && kvi < kvmax) ? v : -INFINITY;
          p[kvt * 4 + r] = v;
          tm = fmaxf(tm, v);
        }
    }
    tm = fmaxf(tm, __shfl_xor(tm, 16));
    tm = fmaxf(tm, __shfl_xor(tm, 32));
    if (!__all(tm <= m)) {  // defer-rescale: skip when no row's max grew
      float mnew = fmaxf(m, tm);
      float fac = exp2f(m - mnew);
      l *= fac;
#pragma unroll
      for (int d4 = 0; d4 < 4; d4++) {
        ot[d4][0] *= fac; ot[d4][1] *= fac; ot[d4][2] *= fac; ot[d4][3] *= fac;
      }
      m = mnew;
    }
    float ls = 0.f;
#pragma unroll
    for (int i = 0; i < 16; i++) {
      float e = exp2f(p[i] - m);  // masked (-inf) -> 0
      p[i] = e;
      ls += e;
    }
    ls += __shfl_xor(ls, 16);
    ls += __shfl_xor(ls, 32);
    l += ls;
    // ---- P -> wave-private LDS (no barrier: same-wave ds ordering) ----
#pragma unroll
    for (int kvt = 0; kvt < 4; kvt++) {
      unsigned w0 = (unsigned)f2bf(p[kvt * 4 + 0]) | ((unsigned)f2bf(p[kvt * 4 + 1]) << 16);
      unsigned w1 = (unsigned)f2bf(p[kvt * 4 + 2]) | ((unsigned)f2bf(p[kvt * 4 + 3]) << 16);
      uint2 pk = {w0, w1};
      *(uint2*)(Pw + lr * 72 + kvt * 16 + lg * 4) = pk;
    }
    s16x8 bp0 = *(const s16x8*)(Pw + lr * 72 + lg * 8);
    s16x8 bp1 = *(const s16x8*)(Pw + lr * 72 + 32 + lg * 8);
    // ---- PV: O^T[d 64][q 16], V^T fragments direct from global ----
    __builtin_amdgcn_s_setprio(1);
#pragma unroll
    for (int d4 = 0; d4 < 4; d4++) {
      const u16* va = vb + (size_t)(d4 * 16 + lr) * vrow + kv0 + lg * 8;
      ot[d4] = mfma16(*(const s16x8*)(va), bp0, ot[d4]);
      ot[d4] = mfma16(*(const s16x8*)(va + 32), bp1, ot[d4]);
    }
    __builtin_amdgcn_s_setprio(0);
  }
  float inv = 1.f / l;
  int b = bh >> 4, h = bh & 15;
  float* op = outg + ((size_t)((b << 10) + qrow) << 10) + h * 64;
#pragma unroll
  for (int d4 = 0; d4 < 4; d4++) {
    f32x4 v;
#pragma unroll
    for (int c = 0; c < 4; c++) v[c] = ot[d4][c] * inv;
    *(f32x4*)(op + d4 * 16 + lg * 4) = v;
  }
}

// ---------------- row LayerNorm over C=1024, in place ----------------
__global__ __launch_bounds__(256) void ln_rows(float* __restrict__ x,
                                               const float* __restrict__ w,
                                               const float* __restrict__ b) {
  __shared__ float red[8];
  size_t row = blockIdx.x;
  float* xr = x + (row << 10);
  int tid = threadIdx.x;
  f32x4 v = *(const f32x4*)(xr + tid * 4);
  float s = v[0] + v[1] + v[2] + v[3];
  float q = v[0] * v[0] + v[1] * v[1] + v[2] * v[2] + v[3] * v[3];
#pragma unroll
  for (int off = 32; off >= 1; off >>= 1) {
    s += __shfl_xor(s, off);
    q += __shfl_xor(q, off);
  }
  int wid = tid >> 6;
  if ((tid & 63) == 0) { red[wid * 2] = s; red[wid * 2 + 1] = q; }
  __syncthreads();
  s = red[0] + red[2] + red[4] + red[6];
  q = red[1] + red[3] + red[5] + red[7];
  float mean = s * (1.0f / 1024.0f);
  float var = q * (1.0f / 1024.0f) - mean * mean;
  float rstd = rsqrtf(fmaxf(var, 0.f) + 1e-5f);
  f32x4 wv = *(const f32x4*)(w + tid * 4);
  f32x4 bv = *(const f32x4*)(b + tid * 4);
  f32x4 o;
#pragma unroll
  for (int c = 0; c < 4; c++) o[c] = (v[c] - mean) * rstd * wv[c] + bv[c];
  *(f32x4*)(xr + tid * 4) = o;
}

// ---------------- gating ----------------
__global__ __launch_bounds__(256) void gate_partial(const float* __restrict__ ln,
                                                    const float* __restrict__ comp,
                                                    const float* __restrict__ w1,
                                                    float* __restrict__ partial) {
  __shared__ float f[4][32];
  int ib = blockIdx.x, i0 = ib * 32, tid = threadIdx.x;
  if (tid < 128) {
    int bb = tid >> 5, ii = tid & 31;
    int i = i0 + ii;
    const float* src = (i < 1024) ? ln : comp;
    int ic = i & 1023;
    f[bb][ii] = src[((size_t)(bb * 1024 + 1023) << 10) + ic];
  }
  __syncthreads();
  float acc[4][4] = {};
  for (int ii = 0; ii < 32; ii++) {
    float f0 = f[0][ii], f1 = f[1][ii], f2 = f[2][ii], f3 = f[3][ii];
#pragma unroll
    for (int jj = 0; jj < 4; jj++) {
      float w = w1[(size_t)(i0 + ii) * 1024 + jj * 256 + tid];
      acc[jj][0] += f0 * w; acc[jj][1] += f1 * w;
      acc[jj][2] += f2 * w; acc[jj][3] += f3 * w;
    }
  }
#pragma unroll
  for (int jj = 0; jj < 4; jj++)
#pragma unroll
    for (int bb = 0; bb < 4; bb++)
      partial[(size_t)((ib << 2) + bb) * 1024 + jj * 256 + tid] = acc[jj][bb];
}

__global__ __launch_bounds__(1024) void gate_finish(const float* __restrict__ partial,
                                                    const float* __restrict__ b1,
                                                    const float* __restrict__ lnw,
                                                    const float* __restrict__ lnb,
                                                    const float* __restrict__ w2,
                                                    const float* __restrict__ b2,
                                                    float* __restrict__ g) {
  __shared__ float redA[16], redB[16];
  int b = blockIdx.x, j = threadIdx.x;
  float s = b1[j];
#pragma unroll 4
  for (int ib = 0; ib < 64; ib++) s += partial[(size_t)((ib << 2) + b) * 1024 + j];
  float sa = s, sb = s * s;
#pragma unroll
  for (int off = 32; off >= 1; off >>= 1) {
    sa += __shfl_xor(sa, off);
    sb += __shfl_xor(sb, off);
  }
  int wid = j >> 6;
  if ((j & 63) == 0) { redA[wid] = sa; redB[wid] = sb; }
  __syncthreads();
  if (j == 0) {
    float A = 0, Bv = 0;
    for (int k2 = 0; k2 < 16; k2++) { A += redA[k2]; Bv += redB[k2]; }
    redA[0] = A; redB[0] = Bv;
  }
  __syncthreads();
  float S = redA[0], Q = redB[0];
  float mean = S * (1.f / 1024.f), var = Q * (1.f / 1024.f) - mean * mean;
  float rstd = rsqrtf(fmaxf(var, 0.f) + 1e-5f);
  float hn = (s - mean) * rstd * lnw[j] + lnb[j];
  hn = fmaxf(hn, 0.f);
  float c0 = hn * w2[j * 2], c1 = hn * w2[j * 2 + 1];
  __syncthreads();
  float ra = c0, rb = c1;
#pragma unroll
  for (int off = 32; off >= 1; off >>= 1) {
    ra += __shfl_xor(ra, off);
    rb += __shfl_xor(rb, off);
  }
  if ((j & 63) == 0) { redA[wid] = ra; redB[wid] = rb; }
  __syncthreads();
  if (j == 0) {
    float A = 0, Bv = 0;
    for (int k2 = 0; k2 < 16; k2++) { A += redA[k2]; Bv += redB[k2]; }
    A += b2[0]; Bv += b2[1];
    float mx = fmaxf(A, Bv);
    float e0 = __expf(A - mx), e1 = __expf(Bv - mx);
    float inv = 1.f / (e0 + e1);
    g[b * 2] = e0 * inv;
    g[b * 2 + 1] = e1 * inv;
  }
}

// combined = g0*local_norm + g1*comp  (bf16 out)
__global__ __launch_bounds__(256) void combine_k(const float* __restrict__ ln,
                                                 const float* __restrict__ comp,
                                                 const float* __restrict__ g,
                                                 u16* __restrict__ out) {
  size_t i = (size_t)blockIdx.x * 256 + threadIdx.x;
  size_t off = i << 2;
  int b = (int)(off >> 20);
  float g0 = g[b * 2], g1 = g[b * 2 + 1];
  f32x4 a = *(const f32x4*)(ln + off);
  f32x4 c = *(const f32x4*)(comp + off);
  u16x4 o = {f2bf(g0 * a[0] + g1 * c[0]), f2bf(g0 * a[1] + g1 * c[1]),
             f2bf(g0 * a[2] + g1 * c[2]), f2bf(g0 * a[3] + g1 * c[3])};
  *(u16x4*)(out + off) = o;
}

// ---------------- host launch ----------------
extern "C" void kernel_launch(void* const* d_in, const int* in_sizes, int n_in,
                              void* d_out, int out_size, void* d_ws, size_t ws_size,
                              hipStream_t stream) {
  const float* x        = (const float*)d_in[0];
  const float* c_attn_w = (const float*)d_in[1];
  const float* c_attn_b = (const float*)d_in[2];
  const float* c_proj_w = (const float*)d_in[3];
  const float* c_proj_b = (const float*)d_in[4];
  const float* conv_w   = (const float*)d_in[5];
  const float* conv_b   = (const float*)d_in[6];
  const float* comp_ln_w= (const float*)d_in[7];
  const float* comp_ln_b= (const float*)d_in[8];
  const float* ln_loc_w = (const float*)d_in[9];
  const float* ln_loc_b = (const float*)d_in[10];
  const float* gate_w1  = (const float*)d_in[11];
  const float* gate_b1  = (const float*)d_in[12];
  const float* gate_ln_w= (const float*)d_in[13];
  const float* gate_ln_b= (const float*)d_in[14];
  const float* gate_w2  = (const float*)d_in[15];
  const float* gate_b2  = (const float*)d_in[16];
  float* out = (float*)d_out;

  char* ws = (char*)d_ws;
  size_t off = 0;
  auto alloc = [&](size_t bytes) -> char* {
    char* p = ws + off;
    off += (bytes + 255) & ~(size_t)255;
    return p;
  };
  u16* x_bf     = (u16*)alloc(8388608);   // reused as `combined` after QKV GEMM
  u16* attn_wT  = (u16*)alloc(6291456);
  u16* proj_wT  = (u16*)alloc(2097152);
  u16* conv_wbf = (u16*)alloc(262144);
  u16* q_bf     = (u16*)alloc(8388608);
  u16* k_bf     = (u16*)alloc(8388608);
  u16* kT_bf    = (u16*)alloc(8388608);
  u16* vT_bf    = (u16*)alloc(8388608);
  u16* k_comp   = (u16*)alloc(524288);
  u16* v_compT  = (u16*)alloc(524288);
  float* local  = (float*)alloc(16777216);
  float* comp   = (float*)alloc(16777216);
  float* partial= (float*)alloc(1048576);
  float* gbuf   = (float*)alloc(256);
  u16* combined = x_bf;  // x_bf dead after gemm_qkv
  if (off > ws_size) return;

  // 1. casts / transposes
  cast_bf16<<<dim3(4096), dim3(256), 0, stream>>>(x, x_bf, 1048576);
  transpose_cast<<<dim3(96, 32), dim3(256), 0, stream>>>(c_attn_w, attn_wT, 1024, 3072);
  transpose_cast<<<dim3(32, 32), dim3(256), 0, stream>>>(c_proj_w, proj_wT, 1024, 1024);
  cast_bf16<<<dim3(128), dim3(256), 0, stream>>>(conv_w, conv_wbf, 32768);

  // 2. QKV GEMM + scatter
  gemm_qkv<<<dim3(32, 24), dim3(256), 0, stream>>>(x_bf, attn_wT, c_attn_b,
                                                   q_bf, k_bf, kT_bf, vT_bf);

  // 3. conv compression (k and v)
  conv_comp<<<dim3(64, 2), dim3(256), 0, stream>>>(kT_bf, vT_bf, conv_wbf, conv_b,
                                                   comp_ln_w, comp_ln_b, k_comp, v_compT);

  // 4. local causal flash attention (barrier-free, L2-direct K/V)
  flash64<<<dim3(1024), dim3(256), 0, stream>>>(q_bf, k_bf, vT_bf, local,
                                                65536, 65536, 1024, 1024);
  // 5. compressed attention (1 KV tile)
  flash64<<<dim3(1024), dim3(256), 0, stream>>>(q_bf, k_comp, v_compT, comp,
                                                4096, 4096, 64, 63);

  // 6. LN(local) in place
  ln_rows<<<dim3(4096), dim3(256), 0, stream>>>(local, ln_loc_w, ln_loc_b);

  // 7. gate MLP
  gate_partial<<<dim3(64), dim3(256), 0, stream>>>(local, comp, gate_w1, partial);
  gate_finish<<<dim3(4), dim3(1024), 0, stream>>>(partial, gate_b1, gate_ln_w,
                                                  gate_ln_b, gate_w2, gate_b2, gbuf);

  // 8. combine + output projection
  combine_k<<<dim3(4096), dim3(256), 0, stream>>>(local, comp, gbuf, combined);
  gemm_proj<<<dim3(32, 8), dim3(256), 0, stream>>>(combined, proj_wT, c_proj_b, out);
}

// Round 5
// 301.643 us; speedup vs baseline: 1.1075x; 1.1075x over previous
//
#include <hip/hip_runtime.h>

using u16 = unsigned short;
using f32x4 = __attribute__((ext_vector_type(4))) float;
using s16x8 = __attribute__((ext_vector_type(8))) short;
using u16x4 = __attribute__((ext_vector_type(4))) unsigned short;

__device__ __forceinline__ u16 f2bf(float f) {
  unsigned u = __float_as_uint(f);
  return (u16)((u + 0x7FFFu + ((u >> 16) & 1u)) >> 16);
}

__device__ __forceinline__ f32x4 mfma16(s16x8 a, s16x8 b, f32x4 c) {
  return __builtin_amdgcn_mfma_f32_16x16x32_bf16(a, b, c, 0, 0, 0);
}

__device__ __forceinline__ void gld16(const void* g, void* l) {
  __builtin_amdgcn_global_load_lds(
      (const __attribute__((address_space(1))) unsigned int*)g,
      (__attribute__((address_space(3))) unsigned int*)l, 16, 0, 0);
}

// ---------------- elementwise casts ----------------
__global__ __launch_bounds__(256) void cast_bf16(const float* __restrict__ in,
                                                 u16* __restrict__ out, int n4) {
  int i = blockIdx.x * 256 + threadIdx.x;
  if (i >= n4) return;
  f32x4 v = *(const f32x4*)(in + (size_t)i * 4);
  u16x4 o = {f2bf(v[0]), f2bf(v[1]), f2bf(v[2]), f2bf(v[3])};
  *(u16x4*)(out + (size_t)i * 4) = o;
}

// in: (R, C) f32 row-major  ->  out: (C, R) bf16 row-major
__global__ __launch_bounds__(256) void transpose_cast(const float* __restrict__ in,
                                                      u16* __restrict__ out,
                                                      int R, int C) {
  __shared__ float t[32][33];
  int bx = blockIdx.x, by = blockIdx.y;
  int tx = threadIdx.x & 31, ty = threadIdx.x >> 5;  // ty 0..7
#pragma unroll
  for (int r = 0; r < 4; r++) {
    int row = by * 32 + ty + r * 8;
    t[ty + r * 8][tx] = in[(size_t)row * C + bx * 32 + tx];
  }
  __syncthreads();
#pragma unroll
  for (int r = 0; r < 4; r++) {
    int orow = bx * 32 + ty + r * 8;
    out[(size_t)orow * R + by * 32 + tx] = f2bf(t[tx][ty + r * 8]);
  }
}

// ---------------- GEMM mainloop (A: MxK bf16, Bt: NxK bf16) ----------------
__device__ __forceinline__ void gemm_mainloop(const u16* A, const u16* Bt, int K,
                                              u16* As, u16* Bs, f32x4 acc[4][4]) {
  const int tid = threadIdx.x;
  const int row = tid >> 2, c16 = tid & 3;
  const int lane = tid & 63, wid = tid >> 6;
  const int wm = wid >> 1, wn = wid & 1, lg = lane >> 4, lr = lane & 15;
  const u16* ga = A + (size_t)row * K + c16 * 8;
  const u16* gb = Bt + (size_t)row * K + c16 * 8;
  const size_t rowskip = (size_t)64 * K;
  for (int k0 = 0; k0 < K; k0 += 32) {
    gld16(ga + k0, As + tid * 8);
    gld16(ga + rowskip + k0, As + 2048 + tid * 8);
    gld16(gb + k0, Bs + tid * 8);
    gld16(gb + rowskip + k0, Bs + 2048 + tid * 8);
    __syncthreads();
    s16x8 af[4], bfr[4];
#pragma unroll
    for (int i = 0; i < 4; i++)
      af[i] = *(const s16x8*)(As + (wm * 64 + i * 16 + lr) * 32 + lg * 8);
#pragma unroll
    for (int j = 0; j < 4; j++)
      bfr[j] = *(const s16x8*)(Bs + (wn * 64 + j * 16 + lr) * 32 + lg * 8);
#pragma unroll
    for (int i = 0; i < 4; i++)
#pragma unroll
      for (int j = 0; j < 4; j++) acc[i][j] = mfma16(af[i], bfr[j], acc[i][j]);
    __syncthreads();
  }
}

// QKV GEMM: x_bf (4096x1024) @ attn_wT (3072x1024)^T + bias -> scatter q,k,kT,vT (bf16)
__global__ __launch_bounds__(256) void gemm_qkv(const u16* __restrict__ A,
                                                const u16* __restrict__ Bt,
                                                const float* __restrict__ bias,
                                                u16* __restrict__ qo, u16* __restrict__ ko,
                                                u16* __restrict__ kTo, u16* __restrict__ vTo) {
  __shared__ u16 As[4096];
  __shared__ u16 Bs[4096];
  int m0 = blockIdx.x * 128, n0 = blockIdx.y * 128;
  f32x4 acc[4][4] = {};
  gemm_mainloop(A + (size_t)m0 * 1024, Bt + (size_t)n0 * 1024, 1024, As, Bs, acc);
  int lane = threadIdx.x & 63, wid = threadIdx.x >> 6;
  int wm = wid >> 1, wn = wid & 1, lg = lane >> 4, lr = lane & 15;
#pragma unroll
  for (int i = 0; i < 4; i++) {
    int mb = m0 + wm * 64 + i * 16 + lg * 4;
    int b = mb >> 10, tb = mb & 1023;
#pragma unroll
    for (int j = 0; j < 4; j++) {
      int n = n0 + wn * 64 + j * 16 + lr;
      float bs = bias[n];
      int sel = n >> 10, hd = n & 1023, h = hd >> 6, d = hd & 63;
      int bh = b * 16 + h;
      u16 u0 = f2bf(acc[i][j][0] + bs), u1 = f2bf(acc[i][j][1] + bs);
      u16 u2 = f2bf(acc[i][j][2] + bs), u3 = f2bf(acc[i][j][3] + bs);
      if (sel == 0) {
        u16* qp = qo + ((size_t)bh << 16) + ((size_t)tb << 6) + d;
        qp[0] = u0; qp[64] = u1; qp[128] = u2; qp[192] = u3;
      } else if (sel == 1) {
        u16* kp = ko + ((size_t)bh << 16) + ((size_t)tb << 6) + d;
        kp[0] = u0; kp[64] = u1; kp[128] = u2; kp[192] = u3;
        u16x4 pk = {u0, u1, u2, u3};
        *(u16x4*)(kTo + ((size_t)(bh * 64 + d) << 10) + tb) = pk;
      } else {
        u16x4 pk = {u0, u1, u2, u3};
        *(u16x4*)(vTo + ((size_t)(bh * 64 + d) << 10) + tb) = pk;
      }
    }
  }
}

// proj GEMM: combined (4096x1024) @ proj_wT (1024x1024)^T + bias -> f32 out
__global__ __launch_bounds__(256) void gemm_proj(const u16* __restrict__ A,
                                                 const u16* __restrict__ Bt,
                                                 const float* __restrict__ bias,
                                                 float* __restrict__ out) {
  __shared__ u16 As[4096];
  __shared__ u16 Bs[4096];
  int m0 = blockIdx.x * 128, n0 = blockIdx.y * 128;
  f32x4 acc[4][4] = {};
  gemm_mainloop(A + (size_t)m0 * 1024, Bt + (size_t)n0 * 1024, 1024, As, Bs, acc);
  int lane = threadIdx.x & 63, wid = threadIdx.x >> 6;
  int wm = wid >> 1, wn = wid & 1, lg = lane >> 4, lr = lane & 15;
#pragma unroll
  for (int i = 0; i < 4; i++) {
    int mb = m0 + wm * 64 + i * 16 + lg * 4;
#pragma unroll
    for (int j = 0; j < 4; j++) {
      int n = n0 + wn * 64 + j * 16 + lr;
      float bs = bias[n];
#pragma unroll
      for (int r = 0; r < 4; r++)
        out[(size_t)(mb + r) * 1024 + n] = acc[i][j][r] + bs;
    }
  }
}

// ---------------- conv compression (+bias,+LN,+GeLU) ----------------
__global__ __launch_bounds__(256) void conv_comp(const u16* __restrict__ kT,
                                                 const u16* __restrict__ vT,
                                                 const u16* __restrict__ cw,
                                                 const float* __restrict__ cb,
                                                 const float* __restrict__ lnw,
                                                 const float* __restrict__ lnb,
                                                 u16* __restrict__ kcomp,
                                                 u16* __restrict__ vcompT) {
  int bh = blockIdx.x, sel = blockIdx.y;
  const u16* src = (sel ? vT : kT) + ((size_t)bh << 16);
  int tid = threadIdx.x, wid = tid >> 6, lane = tid & 63, lg = lane >> 4, lr = lane & 15;
  f32x4 acc[4] = {};
  int arow = wid * 16 + lr;
  if (arow > 62) arow = 62;  // op=63 masked; avoid OOB window
  const u16* abase = src + (size_t)arow * 16 + lg * 8;
#pragma unroll 4
  for (int ic = 0; ic < 64; ic++) {
    s16x8 a = *(const s16x8*)(abase + ic * 1024);
#pragma unroll
    for (int j = 0; j < 4; j++) {
      s16x8 bfr = *(const s16x8*)(cw + (size_t)(j * 16 + lr) * 2048 + ic * 32 + lg * 8);
      acc[j] = mfma16(a, bfr, acc[j]);
    }
  }
  float lwv[4], lbv[4];
#pragma unroll
  for (int j = 0; j < 4; j++) {
    int oc = j * 16 + lr;
    float cbv = cb[oc];
    acc[j][0] += cbv; acc[j][1] += cbv; acc[j][2] += cbv; acc[j][3] += cbv;
    lwv[j] = lnw[oc]; lbv[j] = lnb[oc];
  }
#pragma unroll
  for (int r = 0; r < 4; r++) {
    float s = acc[0][r] + acc[1][r] + acc[2][r] + acc[3][r];
    float q = acc[0][r] * acc[0][r] + acc[1][r] * acc[1][r] +
              acc[2][r] * acc[2][r] + acc[3][r] * acc[3][r];
#pragma unroll
    for (int off = 1; off < 16; off <<= 1) {
      s += __shfl_xor(s, off);
      q += __shfl_xor(q, off);
    }
    float mean = s * (1.f / 64.f);
    float var = q * (1.f / 64.f) - mean * mean;
    float rstd = rsqrtf(fmaxf(var, 0.f) + 1e-5f);
    int op = wid * 16 + lg * 4 + r;
#pragma unroll
    for (int j = 0; j < 4; j++) {
      float y = (acc[j][r] - mean) * rstd * lwv[j] + lbv[j];
      y = 0.5f * y * (1.0f + erff(y * 0.70710678118f));
      if (op > 62) y = 0.f;
      int oc = j * 16 + lr;
      if (sel == 0) kcomp[((size_t)bh << 12) + (op << 6) + oc] = f2bf(y);
      else          vcompT[((size_t)bh << 12) + (oc << 6) + op] = f2bf(y);
    }
  }
}

// ---------------- flash attention v4: K LDS-staged (dbuf), V reg-prefetched ----------------
// 4 waves/block, 64 q-rows; XCD-pinned bh so K/V stay L2-resident.
// K: global_load_lds double-buffer (prefetch t+1 under compute of t), XOR-swizzled.
// V: direct from L2, split-prefetched into regs (lo before QK, hi after QK) = T14.
// Swapped QK^T (mfma(K,Q)); PV as O^T = V^T * P^T; P via wave-private LDS.
__global__ __launch_bounds__(256, 4) void flash64(const u16* __restrict__ qg,
                                                  const u16* __restrict__ kg,
                                                  const u16* __restrict__ vg,
                                                  float* __restrict__ outg,
                                                  int k_bh, int v_bh, int vrow, int kvmax) {
  __shared__ u16 Ks[2][4096];  // [64 kv][64 d] swizzled, double-buffered (16 KB)
  __shared__ u16 Pl[4][1152];  // per-wave P: 16 q-rows x 72 u16 (144B stride, 9 KB)
  const int tid = threadIdx.x;
  const int w = tid >> 6, lane = tid & 63, lg = lane >> 4, lr = lane & 15;
  // XCD-aware decode: bh pinned to one XCD; heavy (long-causal) q-tiles first.
  const int idx = blockIdx.x;
  const int nqt = gridDim.x >> 6;
  const int xcd = idx & 7, j = idx >> 3;
  const int bh = xcd * 8 + (j & 7);
  const int qt0 = nqt - 1 - (j >> 3);
  const int q0 = qt0 * 64;
  const int qrow = q0 + w * 16 + lr;
  const u16* qb = qg + ((size_t)bh << 16) + (size_t)qrow * 64 + lg * 8;
  s16x8 qf0 = *(const s16x8*)(qb);
  s16x8 qf1 = *(const s16x8*)(qb + 32);
  const u16* kb = kg + (size_t)bh * k_bh;
  const u16* vb = vg + (size_t)bh * v_bh;
  int nt = qt0 + 1;
  int ntk = (kvmax + 63) >> 6;
  if (nt > ntk) nt = ntk;
  u16* Pw = Pl[w];
  f32x4 ot[4] = {};
  float m = -INFINITY, l = 0.f;
  const float SCL = 0.125f * 1.44269504089f;  // softmax in exp2 domain

  auto stageK = [&](int bufi, int kv0) {
#pragma unroll
    for (int rnd = 0; rnd < 2; rnd++) {
      int o = tid * 16 + rnd * 4096;          // linear LDS byte offset
      int row = o >> 7;
      int sb = (o & 127) ^ ((row & 7) << 4);  // inverse-swizzled source byte
      gld16(kb + (size_t)(kv0 + row) * 64 + (sb >> 1), &Ks[bufi][o >> 1]);
    }
  };

  stageK(0, 0);
  int cur = 0;
  for (int t = 0; t < nt; t++) {
    __syncthreads();  // staged tile t visible (compiler drains vmcnt)
    if (t + 1 < nt) stageK(cur ^ 1, (t + 1) * 64);
    const int kv0 = t * 64;
    const u16* Kb = Ks[cur];
    const bool full = (kv0 + 63 <= q0 + w * 16) && (kv0 + 64 <= kvmax);
    // ---- V lo-half prefetch (consumed in PV, ~full tile of slack) ----
    s16x8 vlo[4];
#pragma unroll
    for (int d4 = 0; d4 < 4; d4++)
      vlo[d4] = *(const s16x8*)(vb + (size_t)(d4 * 16 + lr) * vrow + kv0 + lg * 8);
    // ---- QK^T: S^T[kv 64][q 16] from staged K ----
    f32x4 st[4];
    __builtin_amdgcn_s_setprio(1);
#pragma unroll
    for (int kvt = 0; kvt < 4; kvt++) {
      int rr = kvt * 16 + lr;
      int sw = (rr & 7) << 4;
      s16x8 k0 = *(const s16x8*)(Kb + (((rr << 7) + ((lg * 16) ^ sw)) >> 1));
      s16x8 k1 = *(const s16x8*)(Kb + (((rr << 7) + ((64 + lg * 16) ^ sw)) >> 1));
      f32x4 z = {};
      z = mfma16(k0, qf0, z);
      z = mfma16(k1, qf1, z);
      st[kvt] = z;
    }
    __builtin_amdgcn_s_setprio(0);
    // ---- V hi-half prefetch (slack: softmax + P roundtrip) ----
    s16x8 vhi[4];
#pragma unroll
    for (int d4 = 0; d4 < 4; d4++)
      vhi[d4] = *(const s16x8*)(vb + (size_t)(d4 * 16 + lr) * vrow + kv0 + 32 + lg * 8);
    // ---- online softmax (lane holds 16 P-values for q=qrow) ----
    float p[16];
    float tm = -INFINITY;
    if (full) {
#pragma unroll
      for (int kvt = 0; kvt < 4; kvt++)
#pragma unroll
        for (int r = 0; r < 4; r++) {
          float v = st[kvt][r] * SCL;
          p[kvt * 4 + r] = v;
          tm = fmaxf(tm, v);
        }
    } else {
#pragma unroll
      for (int kvt = 0; kvt < 4; kvt++)
#pragma unroll
        for (int r = 0; r < 4; r++) {
          int kvi = kv0 + kvt * 16 + lg * 4 + r;
          float v = st[kvt][r] * SCL;
          v = (kvi <= qrow && kvi < kvmax) ? v : -INFINITY;
          p[kvt * 4 + r] = v;
          tm = fmaxf(tm, v);
        }
    }
    tm = fmaxf(tm, __shfl_xor(tm, 16));
    tm = fmaxf(tm, __shfl_xor(tm, 32));
    if (!__all(tm <= m)) {  // defer-rescale: skip when no row's max grew
      float mnew = fmaxf(m, tm);
      float fac = exp2f(m - mnew);
      l *= fac;
#pragma unroll
      for (int d4 = 0; d4 < 4; d4++) {
        ot[d4][0] *= fac; ot[d4][1] *= fac; ot[d4][2] *= fac; ot[d4][3] *= fac;
      }
      m = mnew;
    }
    float ls = 0.f;
#pragma unroll
    for (int i = 0; i < 16; i++) {
      float e = exp2f(p[i] - m);  // masked (-inf) -> 0
      p[i] = e;
      ls += e;
    }
    ls += __shfl_xor(ls, 16);
    ls += __shfl_xor(ls, 32);
    l += ls;
    // ---- P -> wave-private LDS (no barrier: same-wave ds ordering) ----
#pragma unroll
    for (int kvt = 0; kvt < 4; kvt++) {
      unsigned w0 = (unsigned)f2bf(p[kvt * 4 + 0]) | ((unsigned)f2bf(p[kvt * 4 + 1]) << 16);
      unsigned w1 = (unsigned)f2bf(p[kvt * 4 + 2]) | ((unsigned)f2bf(p[kvt * 4 + 3]) << 16);
      uint2 pk = {w0, w1};
      *(uint2*)(Pw + lr * 72 + kvt * 16 + lg * 4) = pk;
    }
    s16x8 bp0 = *(const s16x8*)(Pw + lr * 72 + lg * 8);
    s16x8 bp1 = *(const s16x8*)(Pw + lr * 72 + 32 + lg * 8);
    // ---- PV: O^T[d 64][q 16] from prefetched V regs ----
    __builtin_amdgcn_s_setprio(1);
#pragma unroll
    for (int d4 = 0; d4 < 4; d4++) {
      ot[d4] = mfma16(vlo[d4], bp0, ot[d4]);
      ot[d4] = mfma16(vhi[d4], bp1, ot[d4]);
    }
    __builtin_amdgcn_s_setprio(0);
    cur ^= 1;
  }
  float inv = 1.f / l;
  int b = bh >> 4, h = bh & 15;
  float* op = outg + ((size_t)((b << 10) + qrow) << 10) + h * 64;
#pragma unroll
  for (int d4 = 0; d4 < 4; d4++) {
    f32x4 v;
#pragma unroll
    for (int c = 0; c < 4; c++) v[c] = ot[d4][c] * inv;
    *(f32x4*)(op + d4 * 16 + lg * 4) = v;
  }
}

// ---------------- row LayerNorm over C=1024, in place ----------------
__global__ __launch_bounds__(256) void ln_rows(float* __restrict__ x,
                                               const float* __restrict__ w,
                                               const float* __restrict__ b) {
  __shared__ float red[8];
  size_t row = blockIdx.x;
  float* xr = x + (row << 10);
  int tid = threadIdx.x;
  f32x4 v = *(const f32x4*)(xr + tid * 4);
  float s = v[0] + v[1] + v[2] + v[3];
  float q = v[0] * v[0] + v[1] * v[1] + v[2] * v[2] + v[3] * v[3];
#pragma unroll
  for (int off = 32; off >= 1; off >>= 1) {
    s += __shfl_xor(s, off);
    q += __shfl_xor(q, off);
  }
  int wid = tid >> 6;
  if ((tid & 63) == 0) { red[wid * 2] = s; red[wid * 2 + 1] = q; }
  __syncthreads();
  s = red[0] + red[2] + red[4] + red[6];
  q = red[1] + red[3] + red[5] + red[7];
  float mean = s * (1.0f / 1024.0f);
  float var = q * (1.0f / 1024.0f) - mean * mean;
  float rstd = rsqrtf(fmaxf(var, 0.f) + 1e-5f);
  f32x4 wv = *(const f32x4*)(w + tid * 4);
  f32x4 bv = *(const f32x4*)(b + tid * 4);
  f32x4 o;
#pragma unroll
  for (int c = 0; c < 4; c++) o[c] = (v[c] - mean) * rstd * wv[c] + bv[c];
  *(f32x4*)(xr + tid * 4) = o;
}

// ---------------- gating ----------------
__global__ __launch_bounds__(256) void gate_partial(const float* __restrict__ ln,
                                                    const float* __restrict__ comp,
                                                    const float* __restrict__ w1,
                                                    float* __restrict__ partial) {
  __shared__ float f[4][32];
  int ib = blockIdx.x, i0 = ib * 32, tid = threadIdx.x;
  if (tid < 128) {
    int bb = tid >> 5, ii = tid & 31;
    int i = i0 + ii;
    const float* src = (i < 1024) ? ln : comp;
    int ic = i & 1023;
    f[bb][ii] = src[((size_t)(bb * 1024 + 1023) << 10) + ic];
  }
  __syncthreads();
  float acc[4][4] = {};
  for (int ii = 0; ii < 32; ii++) {
    float f0 = f[0][ii], f1 = f[1][ii], f2 = f[2][ii], f3 = f[3][ii];
#pragma unroll
    for (int jj = 0; jj < 4; jj++) {
      float w = w1[(size_t)(i0 + ii) * 1024 + jj * 256 + tid];
      acc[jj][0] += f0 * w; acc[jj][1] += f1 * w;
      acc[jj][2] += f2 * w; acc[jj][3] += f3 * w;
    }
  }
#pragma unroll
  for (int jj = 0; jj < 4; jj++)
#pragma unroll
    for (int bb = 0; bb < 4; bb++)
      partial[(size_t)((ib << 2) + bb) * 1024 + jj * 256 + tid] = acc[jj][bb];
}

__global__ __launch_bounds__(1024) void gate_finish(const float* __restrict__ partial,
                                                    const float* __restrict__ b1,
                                                    const float* __restrict__ lnw,
                                                    const float* __restrict__ lnb,
                                                    const float* __restrict__ w2,
                                                    const float* __restrict__ b2,
                                                    float* __restrict__ g) {
  __shared__ float redA[16], redB[16];
  int b = blockIdx.x, j = threadIdx.x;
  float s = b1[j];
#pragma unroll 4
  for (int ib = 0; ib < 64; ib++) s += partial[(size_t)((ib << 2) + b) * 1024 + j];
  float sa = s, sb = s * s;
#pragma unroll
  for (int off = 32; off >= 1; off >>= 1) {
    sa += __shfl_xor(sa, off);
    sb += __shfl_xor(sb, off);
  }
  int wid = j >> 6;
  if ((j & 63) == 0) { redA[wid] = sa; redB[wid] = sb; }
  __syncthreads();
  if (j == 0) {
    float A = 0, Bv = 0;
    for (int k2 = 0; k2 < 16; k2++) { A += redA[k2]; Bv += redB[k2]; }
    redA[0] = A; redB[0] = Bv;
  }
  __syncthreads();
  float S = redA[0], Q = redB[0];
  float mean = S * (1.f / 1024.f), var = Q * (1.f / 1024.f) - mean * mean;
  float rstd = rsqrtf(fmaxf(var, 0.f) + 1e-5f);
  float hn = (s - mean) * rstd * lnw[j] + lnb[j];
  hn = fmaxf(hn, 0.f);
  float c0 = hn * w2[j * 2], c1 = hn * w2[j * 2 + 1];
  __syncthreads();
  float ra = c0, rb = c1;
#pragma unroll
  for (int off = 32; off >= 1; off >>= 1) {
    ra += __shfl_xor(ra, off);
    rb += __shfl_xor(rb, off);
  }
  if ((j & 63) == 0) { redA[wid] = ra; redB[wid] = rb; }
  __syncthreads();
  if (j == 0) {
    float A = 0, Bv = 0;
    for (int k2 = 0; k2 < 16; k2++) { A += redA[k2]; Bv += redB[k2]; }
    A += b2[0]; Bv += b2[1];
    float mx = fmaxf(A, Bv);
    float e0 = __expf(A - mx), e1 = __expf(Bv - mx);
    float inv = 1.f / (e0 + e1);
    g[b * 2] = e0 * inv;
    g[b * 2 + 1] = e1 * inv;
  }
}

// combined = g0*local_norm + g1*comp  (bf16 out)
__global__ __launch_bounds__(256) void combine_k(const float* __restrict__ ln,
                                                 const float* __restrict__ comp,
                                                 const float* __restrict__ g,
                                                 u16* __restrict__ out) {
  size_t i = (size_t)blockIdx.x * 256 + threadIdx.x;
  size_t off = i << 2;
  int b = (int)(off >> 20);
  float g0 = g[b * 2], g1 = g[b * 2 + 1];
  f32x4 a = *(const f32x4*)(ln + off);
  f32x4 c = *(const f32x4*)(comp + off);
  u16x4 o = {f2bf(g0 * a[0] + g1 * c[0]), f2bf(g0 * a[1] + g1 * c[1]),
             f2bf(g0 * a[2] + g1 * c[2]), f2bf(g0 * a[3] + g1 * c[3])};
  *(u16x4*)(out + off) = o;
}

// ---------------- host launch ----------------
extern "C" void kernel_launch(void* const* d_in, const int* in_sizes, int n_in,
                              void* d_out, int out_size, void* d_ws, size_t ws_size,
                              hipStream_t stream) {
  const float* x        = (const float*)d_in[0];
  const float* c_attn_w = (const float*)d_in[1];
  const float* c_attn_b = (const float*)d_in[2];
  const float* c_proj_w = (const float*)d_in[3];
  const float* c_proj_b = (const float*)d_in[4];
  const float* conv_w   = (const float*)d_in[5];
  const float* conv_b   = (const float*)d_in[6];
  const float* comp_ln_w= (const float*)d_in[7];
  const float* comp_ln_b= (const float*)d_in[8];
  const float* ln_loc_w = (const float*)d_in[9];
  const float* ln_loc_b = (const float*)d_in[10];
  const float* gate_w1  = (const float*)d_in[11];
  const float* gate_b1  = (const float*)d_in[12];
  const float* gate_ln_w= (const float*)d_in[13];
  const float* gate_ln_b= (const float*)d_in[14];
  const float* gate_w2  = (const float*)d_in[15];
  const float* gate_b2  = (const float*)d_in[16];
  float* out = (float*)d_out;

  char* ws = (char*)d_ws;
  size_t off = 0;
  auto alloc = [&](size_t bytes) -> char* {
    char* p = ws + off;
    off += (bytes + 255) & ~(size_t)255;
    return p;
  };
  u16* x_bf     = (u16*)alloc(8388608);   // reused as `combined` after QKV GEMM
  u16* attn_wT  = (u16*)alloc(6291456);
  u16* proj_wT  = (u16*)alloc(2097152);
  u16* conv_wbf = (u16*)alloc(262144);
  u16* q_bf     = (u16*)alloc(8388608);
  u16* k_bf     = (u16*)alloc(8388608);
  u16* kT_bf    = (u16*)alloc(8388608);
  u16* vT_bf    = (u16*)alloc(8388608);
  u16* k_comp   = (u16*)alloc(524288);
  u16* v_compT  = (u16*)alloc(524288);
  float* local  = (float*)alloc(16777216);
  float* comp   = (float*)alloc(16777216);
  float* partial= (float*)alloc(1048576);
  float* gbuf   = (float*)alloc(256);
  u16* combined = x_bf;  // x_bf dead after gemm_qkv
  if (off > ws_size) return;

  // 1. casts / transposes
  cast_bf16<<<dim3(4096), dim3(256), 0, stream>>>(x, x_bf, 1048576);
  transpose_cast<<<dim3(96, 32), dim3(256), 0, stream>>>(c_attn_w, attn_wT, 1024, 3072);
  transpose_cast<<<dim3(32, 32), dim3(256), 0, stream>>>(c_proj_w, proj_wT, 1024, 1024);
  cast_bf16<<<dim3(128), dim3(256), 0, stream>>>(conv_w, conv_wbf, 32768);

  // 2. QKV GEMM + scatter
  gemm_qkv<<<dim3(32, 24), dim3(256), 0, stream>>>(x_bf, attn_wT, c_attn_b,
                                                   q_bf, k_bf, kT_bf, vT_bf);

  // 3. conv compression (k and v)
  conv_comp<<<dim3(64, 2), dim3(256), 0, stream>>>(kT_bf, vT_bf, conv_wbf, conv_b,
                                                   comp_ln_w, comp_ln_b, k_comp, v_compT);

  // 4. local causal flash attention (K staged, V reg-prefetched, XCD-pinned)
  flash64<<<dim3(1024), dim3(256), 0, stream>>>(q_bf, k_bf, vT_bf, local,
                                                65536, 65536, 1024, 1024);
  // 5. compressed attention (1 KV tile)
  flash64<<<dim3(1024), dim3(256), 0, stream>>>(q_bf, k_comp, v_compT, comp,
                                                4096, 4096, 64, 63);

  // 6. LN(local) in place
  ln_rows<<<dim3(4096), dim3(256), 0, stream>>>(local, ln_loc_w, ln_loc_b);

  // 7. gate MLP
  gate_partial<<<dim3(64), dim3(256), 0, stream>>>(local, comp, gate_w1, partial);
  gate_finish<<<dim3(4), dim3(1024), 0, stream>>>(partial, gate_b1, gate_ln_w,
                                                  gate_ln_b, gate_w2, gate_b2, gbuf);

  // 8. combine + output projection
  combine_k<<<dim3(4096), dim3(256), 0, stream>>>(local, comp, gbuf, combined);
  gemm_proj<<<dim3(32, 8), dim3(256), 0, stream>>>(combined, proj_wT, c_proj_b, out);
}

// Round 7
// 279.614 us; speedup vs baseline: 1.1948x; 1.0788x over previous
//
#include <hip/hip_runtime.h>

using u16 = unsigned short;
using f32x4 = __attribute__((ext_vector_type(4))) float;
using s16x8 = __attribute__((ext_vector_type(8))) short;
using u16x4 = __attribute__((ext_vector_type(4))) unsigned short;

__device__ __forceinline__ u16 f2bf(float f) {
  unsigned u = __float_as_uint(f);
  return (u16)((u + 0x7FFFu + ((u >> 16) & 1u)) >> 16);
}

__device__ __forceinline__ f32x4 mfma16(s16x8 a, s16x8 b, f32x4 c) {
  return __builtin_amdgcn_mfma_f32_16x16x32_bf16(a, b, c, 0, 0, 0);
}

__device__ __forceinline__ void gld16(const void* g, void* l) {
  __builtin_amdgcn_global_load_lds(
      (const __attribute__((address_space(1))) unsigned int*)g,
      (__attribute__((address_space(3))) unsigned int*)l, 16, 0, 0);
}

// ---------------- elementwise casts ----------------
__global__ __launch_bounds__(256) void cast_bf16(const float* __restrict__ in,
                                                 u16* __restrict__ out, int n4) {
  int i = blockIdx.x * 256 + threadIdx.x;
  if (i >= n4) return;
  f32x4 v = *(const f32x4*)(in + (size_t)i * 4);
  u16x4 o = {f2bf(v[0]), f2bf(v[1]), f2bf(v[2]), f2bf(v[3])};
  *(u16x4*)(out + (size_t)i * 4) = o;
}

// conv weights -> MFMA-fragment order:
// wfrag[((ic*4 + j)*64 + lr*4 + lg)*8 + e] = w[(j*16+lr)*2048 + ic*32 + lg*8 + e]
// so a wave's B-fragment load for (ic,j) is one contiguous 1KB read.
// 64 ic x 4 j x 64 lanes x 8 elems = 131072 u16 -> 16384 threads = 64 blocks.
__global__ __launch_bounds__(256) void cast_wfrag(const float* __restrict__ in,
                                                  u16* __restrict__ out) {
  int t = blockIdx.x * 256 + threadIdx.x;  // 0..16383 fragment-piece id
  int c = t & 63, blk = t >> 6;            // blk = ic*4 + j, 0..255
  int j = blk & 3, ic = blk >> 2;
  int lr = c >> 2, lg = c & 3;
  const float* src = in + (size_t)(j * 16 + lr) * 2048 + ic * 32 + lg * 8;
  f32x4 a = *(const f32x4*)(src);
  f32x4 b = *(const f32x4*)(src + 4);
  u16* dst = out + (size_t)t * 8;
  u16x4 o0 = {f2bf(a[0]), f2bf(a[1]), f2bf(a[2]), f2bf(a[3])};
  u16x4 o1 = {f2bf(b[0]), f2bf(b[1]), f2bf(b[2]), f2bf(b[3])};
  *(u16x4*)(dst) = o0;
  *(u16x4*)(dst + 4) = o1;
}

// in: (R, C) f32 row-major  ->  out: (C, R) bf16 row-major
__global__ __launch_bounds__(256) void transpose_cast(const float* __restrict__ in,
                                                      u16* __restrict__ out,
                                                      int R, int C) {
  __shared__ float t[32][33];
  int bx = blockIdx.x, by = blockIdx.y;
  int tx = threadIdx.x & 31, ty = threadIdx.x >> 5;  // ty 0..7
#pragma unroll
  for (int r = 0; r < 4; r++) {
    int row = by * 32 + ty + r * 8;
    t[ty + r * 8][tx] = in[(size_t)row * C + bx * 32 + tx];
  }
  __syncthreads();
#pragma unroll
  for (int r = 0; r < 4; r++) {
    int orow = bx * 32 + ty + r * 8;
    out[(size_t)orow * R + by * 32 + tx] = f2bf(t[tx][ty + r * 8]);
  }
}

// ---------------- GEMM mainloop (A: MxK bf16, Bt: NxK bf16) ----------------
__device__ __forceinline__ void gemm_mainloop(const u16* A, const u16* Bt, int K,
                                              u16* As, u16* Bs, f32x4 acc[4][4]) {
  const int tid = threadIdx.x;
  const int row = tid >> 2, c16 = tid & 3;
  const int lane = tid & 63, wid = tid >> 6;
  const int wm = wid >> 1, wn = wid & 1, lg = lane >> 4, lr = lane & 15;
  const u16* ga = A + (size_t)row * K + c16 * 8;
  const u16* gb = Bt + (size_t)row * K + c16 * 8;
  const size_t rowskip = (size_t)64 * K;
  for (int k0 = 0; k0 < K; k0 += 32) {
    gld16(ga + k0, As + tid * 8);
    gld16(ga + rowskip + k0, As + 2048 + tid * 8);
    gld16(gb + k0, Bs + tid * 8);
    gld16(gb + rowskip + k0, Bs + 2048 + tid * 8);
    __syncthreads();
    s16x8 af[4], bfr[4];
#pragma unroll
    for (int i = 0; i < 4; i++)
      af[i] = *(const s16x8*)(As + (wm * 64 + i * 16 + lr) * 32 + lg * 8);
#pragma unroll
    for (int j = 0; j < 4; j++)
      bfr[j] = *(const s16x8*)(Bs + (wn * 64 + j * 16 + lr) * 32 + lg * 8);
#pragma unroll
    for (int i = 0; i < 4; i++)
#pragma unroll
      for (int j = 0; j < 4; j++) acc[i][j] = mfma16(af[i], bfr[j], acc[i][j]);
    __syncthreads();
  }
}

// QKV GEMM: x_bf (4096x1024) @ attn_wT (3072x1024)^T + bias -> scatter q,k,kT,vT (bf16)
__global__ __launch_bounds__(256) void gemm_qkv(const u16* __restrict__ A,
                                                const u16* __restrict__ Bt,
                                                const float* __restrict__ bias,
                                                u16* __restrict__ qo, u16* __restrict__ ko,
                                                u16* __restrict__ kTo, u16* __restrict__ vTo) {
  __shared__ u16 As[4096];
  __shared__ u16 Bs[4096];
  int m0 = blockIdx.x * 128, n0 = blockIdx.y * 128;
  f32x4 acc[4][4] = {};
  gemm_mainloop(A + (size_t)m0 * 1024, Bt + (size_t)n0 * 1024, 1024, As, Bs, acc);
  int lane = threadIdx.x & 63, wid = threadIdx.x >> 6;
  int wm = wid >> 1, wn = wid & 1, lg = lane >> 4, lr = lane & 15;
#pragma unroll
  for (int i = 0; i < 4; i++) {
    int mb = m0 + wm * 64 + i * 16 + lg * 4;
    int b = mb >> 10, tb = mb & 1023;
#pragma unroll
    for (int j = 0; j < 4; j++) {
      int n = n0 + wn * 64 + j * 16 + lr;
      float bs = bias[n];
      int sel = n >> 10, hd = n & 1023, h = hd >> 6, d = hd & 63;
      int bh = b * 16 + h;
      u16 u0 = f2bf(acc[i][j][0] + bs), u1 = f2bf(acc[i][j][1] + bs);
      u16 u2 = f2bf(acc[i][j][2] + bs), u3 = f2bf(acc[i][j][3] + bs);
      if (sel == 0) {
        u16* qp = qo + ((size_t)bh << 16) + ((size_t)tb << 6) + d;
        qp[0] = u0; qp[64] = u1; qp[128] = u2; qp[192] = u3;
      } else if (sel == 1) {
        u16* kp = ko + ((size_t)bh << 16) + ((size_t)tb << 6) + d;
        kp[0] = u0; kp[64] = u1; kp[128] = u2; kp[192] = u3;
        u16x4 pk = {u0, u1, u2, u3};
        *(u16x4*)(kTo + ((size_t)(bh * 64 + d) << 10) + tb) = pk;
      } else {
        u16x4 pk = {u0, u1, u2, u3};
        *(u16x4*)(vTo + ((size_t)(bh * 64 + d) << 10) + tb) = pk;
      }
    }
  }
}

// proj GEMM: combined (4096x1024) @ proj_wT (1024x1024)^T + bias -> f32 out
__global__ __launch_bounds__(256) void gemm_proj(const u16* __restrict__ A,
                                                 const u16* __restrict__ Bt,
                                                 const float* __restrict__ bias,
                                                 float* __restrict__ out) {
  __shared__ u16 As[4096];
  __shared__ u16 Bs[4096];
  int m0 = blockIdx.x * 128, n0 = blockIdx.y * 128;
  f32x4 acc[4][4] = {};
  gemm_mainloop(A + (size_t)m0 * 1024, Bt + (size_t)n0 * 1024, 1024, As, Bs, acc);
  int lane = threadIdx.x & 63, wid = threadIdx.x >> 6;
  int wm = wid >> 1, wn = wid & 1, lg = lane >> 4, lr = lane & 15;
#pragma unroll
  for (int i = 0; i < 4; i++) {
    int mb = m0 + wm * 64 + i * 16 + lg * 4;
#pragma unroll
    for (int j = 0; j < 4; j++) {
      int n = n0 + wn * 64 + j * 16 + lr;
      float bs = bias[n];
#pragma unroll
      for (int r = 0; r < 4; r++)
        out[(size_t)(mb + r) * 1024 + n] = acc[i][j][r] + bs;
    }
  }
}

// ---------------- conv compression v2 (+bias,+LN,+GeLU) ----------------
// 8 waves: wave w = (ichalf<<2)|wq; wq owns op rows wq*16..+15, ichalf splits K.
// Weights in fragment order (coalesced 1KB loads). Cross-wave reduce via LDS.
__global__ __launch_bounds__(512, 2) void conv_comp(const u16* __restrict__ kT,
                                                    const u16* __restrict__ vT,
                                                    const u16* __restrict__ wfrag,
                                                    const float* __restrict__ cb,
                                                    const float* __restrict__ lnw,
                                                    const float* __restrict__ lnb,
                                                    u16* __restrict__ kcomp,
                                                    u16* __restrict__ vcompT) {
  __shared__ float red[4][64][16];  // 16 KB: partials from waves 4..7
  int bh = blockIdx.x, sel = blockIdx.y;
  const u16* src = (sel ? vT : kT) + ((size_t)bh << 16);
  int tid = threadIdx.x, w = tid >> 6, lane = tid & 63, lg = lane >> 4, lr = lane & 15;
  int wq = w & 3, ichalf = w >> 2;
  f32x4 acc[4] = {};
  int arow = wq * 16 + lr;
  if (arow > 62) arow = 62;  // op=63 masked; avoid OOB window
  const u16* abase = src + (size_t)arow * 16 + lg * 8;
  const u16* wbase = wfrag + (size_t)(lr * 4 + lg) * 8;
  int ic0 = ichalf * 32;
#pragma unroll 8
  for (int ic = ic0; ic < ic0 + 32; ic++) {
    s16x8 a = *(const s16x8*)(abase + ic * 1024);
    const u16* wrow = wbase + (size_t)ic * 2048;
#pragma unroll
    for (int j = 0; j < 4; j++) {
      s16x8 bfr = *(const s16x8*)(wrow + j * 512);
      acc[j] = mfma16(a, bfr, acc[j]);
    }
  }
  if (w >= 4) {
#pragma unroll
    for (int j = 0; j < 4; j++)
#pragma unroll
      for (int r = 0; r < 4; r++) red[wq][lane][j * 4 + r] = acc[j][r];
  }
  __syncthreads();
  if (w >= 4) return;
#pragma unroll
  for (int j = 0; j < 4; j++)
#pragma unroll
    for (int r = 0; r < 4; r++) acc[j][r] += red[wq][lane][j * 4 + r];
  float lwv[4], lbv[4];
#pragma unroll
  for (int j = 0; j < 4; j++) {
    int oc = j * 16 + lr;
    float cbv = cb[oc];
    acc[j][0] += cbv; acc[j][1] += cbv; acc[j][2] += cbv; acc[j][3] += cbv;
    lwv[j] = lnw[oc]; lbv[j] = lnb[oc];
  }
#pragma unroll
  for (int r = 0; r < 4; r++) {
    float s = acc[0][r] + acc[1][r] + acc[2][r] + acc[3][r];
    float q = acc[0][r] * acc[0][r] + acc[1][r] * acc[1][r] +
              acc[2][r] * acc[2][r] + acc[3][r] * acc[3][r];
#pragma unroll
    for (int off = 1; off < 16; off <<= 1) {
      s += __shfl_xor(s, off);
      q += __shfl_xor(q, off);
    }
    float mean = s * (1.f / 64.f);
    float var = q * (1.f / 64.f) - mean * mean;
    float rstd = rsqrtf(fmaxf(var, 0.f) + 1e-5f);
    int op = wq * 16 + lg * 4 + r;
#pragma unroll
    for (int j = 0; j < 4; j++) {
      float y = (acc[j][r] - mean) * rstd * lwv[j] + lbv[j];
      y = 0.5f * y * (1.0f + erff(y * 0.70710678118f));
      if (op > 62) y = 0.f;
      int oc = j * 16 + lr;
      if (sel == 0) kcomp[((size_t)bh << 12) + (op << 6) + oc] = f2bf(y);
      else          vcompT[((size_t)bh << 12) + (oc << 6) + op] = f2bf(y);
    }
  }
}

// ---------------- flash attention v4: K LDS-staged (dbuf), V reg-prefetched ----------------
__global__ __launch_bounds__(256, 4) void flash64(const u16* __restrict__ qg,
                                                  const u16* __restrict__ kg,
                                                  const u16* __restrict__ vg,
                                                  float* __restrict__ outg,
                                                  int k_bh, int v_bh, int vrow, int kvmax) {
  __shared__ u16 Ks[2][4096];  // [64 kv][64 d] swizzled, double-buffered (16 KB)
  __shared__ u16 Pl[4][1152];  // per-wave P: 16 q-rows x 72 u16 (144B stride, 9 KB)
  const int tid = threadIdx.x;
  const int w = tid >> 6, lane = tid & 63, lg = lane >> 4, lr = lane & 15;
  const int idx = blockIdx.x;
  const int nqt = gridDim.x >> 6;
  const int xcd = idx & 7, j = idx >> 3;
  const int bh = xcd * 8 + (j & 7);
  const int qt0 = nqt - 1 - (j >> 3);
  const int q0 = qt0 * 64;
  const int qrow = q0 + w * 16 + lr;
  const u16* qb = qg + ((size_t)bh << 16) + (size_t)qrow * 64 + lg * 8;
  s16x8 qf0 = *(const s16x8*)(qb);
  s16x8 qf1 = *(const s16x8*)(qb + 32);
  const u16* kb = kg + (size_t)bh * k_bh;
  const u16* vb = vg + (size_t)bh * v_bh;
  int nt = qt0 + 1;
  int ntk = (kvmax + 63) >> 6;
  if (nt > ntk) nt = ntk;
  u16* Pw = Pl[w];
  f32x4 ot[4] = {};
  float m = -INFINITY, l = 0.f;
  const float SCL = 0.125f * 1.44269504089f;  // softmax in exp2 domain

  auto stageK = [&](int bufi, int kv0) {
#pragma unroll
    for (int rnd = 0; rnd < 2; rnd++) {
      int o = tid * 16 + rnd * 4096;          // linear LDS byte offset
      int row = o >> 7;
      int sb = (o & 127) ^ ((row & 7) << 4);  // inverse-swizzled source byte
      gld16(kb + (size_t)(kv0 + row) * 64 + (sb >> 1), &Ks[bufi][o >> 1]);
    }
  };

  stageK(0, 0);
  int cur = 0;
  for (int t = 0; t < nt; t++) {
    __syncthreads();  // staged tile t visible (compiler drains vmcnt)
    if (t + 1 < nt) stageK(cur ^ 1, (t + 1) * 64);
    const int kv0 = t * 64;
    const u16* Kb = Ks[cur];
    const bool full = (kv0 + 63 <= q0 + w * 16) && (kv0 + 64 <= kvmax);
    s16x8 vlo[4];
#pragma unroll
    for (int d4 = 0; d4 < 4; d4++)
      vlo[d4] = *(const s16x8*)(vb + (size_t)(d4 * 16 + lr) * vrow + kv0 + lg * 8);
    f32x4 st[4];
    __builtin_amdgcn_s_setprio(1);
#pragma unroll
    for (int kvt = 0; kvt < 4; kvt++) {
      int rr = kvt * 16 + lr;
      int sw = (rr & 7) << 4;
      s16x8 k0 = *(const s16x8*)(Kb + (((rr << 7) + ((lg * 16) ^ sw)) >> 1));
      s16x8 k1 = *(const s16x8*)(Kb + (((rr << 7) + ((64 + lg * 16) ^ sw)) >> 1));
      f32x4 z = {};
      z = mfma16(k0, qf0, z);
      z = mfma16(k1, qf1, z);
      st[kvt] = z;
    }
    __builtin_amdgcn_s_setprio(0);
    s16x8 vhi[4];
#pragma unroll
    for (int d4 = 0; d4 < 4; d4++)
      vhi[d4] = *(const s16x8*)(vb + (size_t)(d4 * 16 + lr) * vrow + kv0 + 32 + lg * 8);
    float p[16];
    float tm = -INFINITY;
    if (full) {
#pragma unroll
      for (int kvt = 0; kvt < 4; kvt++)
#pragma unroll
        for (int r = 0; r < 4; r++) {
          float v = st[kvt][r] * SCL;
          p[kvt * 4 + r] = v;
          tm = fmaxf(tm, v);
        }
    } else {
#pragma unroll
      for (int kvt = 0; kvt < 4; kvt++)
#pragma unroll
        for (int r = 0; r < 4; r++) {
          int kvi = kv0 + kvt * 16 + lg * 4 + r;
          float v = st[kvt][r] * SCL;
          v = (kvi <= qrow && kvi < kvmax) ? v : -INFINITY;
          p[kvt * 4 + r] = v;
          tm = fmaxf(tm, v);
        }
    }
    tm = fmaxf(tm, __shfl_xor(tm, 16));
    tm = fmaxf(tm, __shfl_xor(tm, 32));
    if (!__all(tm <= m)) {
      float mnew = fmaxf(m, tm);
      float fac = exp2f(m - mnew);
      l *= fac;
#pragma unroll
      for (int d4 = 0; d4 < 4; d4++) {
        ot[d4][0] *= fac; ot[d4][1] *= fac; ot[d4][2] *= fac; ot[d4][3] *= fac;
      }
      m = mnew;
    }
    float ls = 0.f;
#pragma unroll
    for (int i = 0; i < 16; i++) {
      float e = exp2f(p[i] - m);
      p[i] = e;
      ls += e;
    }
    ls += __shfl_xor(ls, 16);
    ls += __shfl_xor(ls, 32);
    l += ls;
#pragma unroll
    for (int kvt = 0; kvt < 4; kvt++) {
      unsigned w0 = (unsigned)f2bf(p[kvt * 4 + 0]) | ((unsigned)f2bf(p[kvt * 4 + 1]) << 16);
      unsigned w1 = (unsigned)f2bf(p[kvt * 4 + 2]) | ((unsigned)f2bf(p[kvt * 4 + 3]) << 16);
      uint2 pk = {w0, w1};
      *(uint2*)(Pw + lr * 72 + kvt * 16 + lg * 4) = pk;
    }
    s16x8 bp0 = *(const s16x8*)(Pw + lr * 72 + lg * 8);
    s16x8 bp1 = *(const s16x8*)(Pw + lr * 72 + 32 + lg * 8);
    __builtin_amdgcn_s_setprio(1);
#pragma unroll
    for (int d4 = 0; d4 < 4; d4++) {
      ot[d4] = mfma16(vlo[d4], bp0, ot[d4]);
      ot[d4] = mfma16(vhi[d4], bp1, ot[d4]);
    }
    __builtin_amdgcn_s_setprio(0);
    cur ^= 1;
  }
  float inv = 1.f / l;
  int b = bh >> 4, h = bh & 15;
  float* op = outg + ((size_t)((b << 10) + qrow) << 10) + h * 64;
#pragma unroll
  for (int d4 = 0; d4 < 4; d4++) {
    f32x4 v;
#pragma unroll
    for (int c = 0; c < 4; c++) v[c] = ot[d4][c] * inv;
    *(f32x4*)(op + d4 * 16 + lg * 4) = v;
  }
}

// ---------------- row LayerNorm over C=1024, in place ----------------
__global__ __launch_bounds__(256) void ln_rows(float* __restrict__ x,
                                               const float* __restrict__ w,
                                               const float* __restrict__ b) {
  __shared__ float red[8];
  size_t row = blockIdx.x;
  float* xr = x + (row << 10);
  int tid = threadIdx.x;
  f32x4 v = *(const f32x4*)(xr + tid * 4);
  float s = v[0] + v[1] + v[2] + v[3];
  float q = v[0] * v[0] + v[1] * v[1] + v[2] * v[2] + v[3] * v[3];
#pragma unroll
  for (int off = 32; off >= 1; off >>= 1) {
    s += __shfl_xor(s, off);
    q += __shfl_xor(q, off);
  }
  int wid = tid >> 6;
  if ((tid & 63) == 0) { red[wid * 2] = s; red[wid * 2 + 1] = q; }
  __syncthreads();
  s = red[0] + red[2] + red[4] + red[6];
  q = red[1] + red[3] + red[5] + red[7];
  float mean = s * (1.0f / 1024.0f);
  float var = q * (1.0f / 1024.0f) - mean * mean;
  float rstd = rsqrtf(fmaxf(var, 0.f) + 1e-5f);
  f32x4 wv = *(const f32x4*)(w + tid * 4);
  f32x4 bv = *(const f32x4*)(b + tid * 4);
  f32x4 o;
#pragma unroll
  for (int c = 0; c < 4; c++) o[c] = (v[c] - mean) * rstd * wv[c] + bv[c];
  *(f32x4*)(xr + tid * 4) = o;
}

// ---------------- gating ----------------
__global__ __launch_bounds__(256) void gate_partial(const float* __restrict__ ln,
                                                    const float* __restrict__ comp,
                                                    const float* __restrict__ w1,
                                                    float* __restrict__ partial) {
  __shared__ float f[4][32];
  int ib = blockIdx.x, i0 = ib * 32, tid = threadIdx.x;
  if (tid < 128) {
    int bb = tid >> 5, ii = tid & 31;
    int i = i0 + ii;
    const float* src = (i < 1024) ? ln : comp;
    int ic = i & 1023;
    f[bb][ii] = src[((size_t)(bb * 1024 + 1023) << 10) + ic];
  }
  __syncthreads();
  float acc[4][4] = {};
  for (int ii = 0; ii < 32; ii++) {
    float f0 = f[0][ii], f1 = f[1][ii], f2 = f[2][ii], f3 = f[3][ii];
#pragma unroll
    for (int jj = 0; jj < 4; jj++) {
      float w = w1[(size_t)(i0 + ii) * 1024 + jj * 256 + tid];
      acc[jj][0] += f0 * w; acc[jj][1] += f1 * w;
      acc[jj][2] += f2 * w; acc[jj][3] += f3 * w;
    }
  }
#pragma unroll
  for (int jj = 0; jj < 4; jj++)
#pragma unroll
    for (int bb = 0; bb < 4; bb++)
      partial[(size_t)((ib << 2) + bb) * 1024 + jj * 256 + tid] = acc[jj][bb];
}

__global__ __launch_bounds__(1024) void gate_finish(const float* __restrict__ partial,
                                                    const float* __restrict__ b1,
                                                    const float* __restrict__ lnw,
                                                    const float* __restrict__ lnb,
                                                    const float* __restrict__ w2,
                                                    const float* __restrict__ b2,
                                                    float* __restrict__ g) {
  __shared__ float redA[16], redB[16];
  int b = blockIdx.x, j = threadIdx.x;
  float s = b1[j];
#pragma unroll 4
  for (int ib = 0; ib < 64; ib++) s += partial[(size_t)((ib << 2) + b) * 1024 + j];
  float sa = s, sb = s * s;
#pragma unroll
  for (int off = 32; off >= 1; off >>= 1) {
    sa += __shfl_xor(sa, off);
    sb += __shfl_xor(sb, off);
  }
  int wid = j >> 6;
  if ((j & 63) == 0) { redA[wid] = sa; redB[wid] = sb; }
  __syncthreads();
  if (j == 0) {
    float A = 0, Bv = 0;
    for (int k2 = 0; k2 < 16; k2++) { A += redA[k2]; Bv += redB[k2]; }
    redA[0] = A; redB[0] = Bv;
  }
  __syncthreads();
  float S = redA[0], Q = redB[0];
  float mean = S * (1.f / 1024.f), var = Q * (1.f / 1024.f) - mean * mean;
  float rstd = rsqrtf(fmaxf(var, 0.f) + 1e-5f);
  float hn = (s - mean) * rstd * lnw[j] + lnb[j];
  hn = fmaxf(hn, 0.f);
  float c0 = hn * w2[j * 2], c1 = hn * w2[j * 2 + 1];
  __syncthreads();
  float ra = c0, rb = c1;
#pragma unroll
  for (int off = 32; off >= 1; off >>= 1) {
    ra += __shfl_xor(ra, off);
    rb += __shfl_xor(rb, off);
  }
  if ((j & 63) == 0) { redA[wid] = ra; redB[wid] = rb; }
  __syncthreads();
  if (j == 0) {
    float A = 0, Bv = 0;
    for (int k2 = 0; k2 < 16; k2++) { A += redA[k2]; Bv += redB[k2]; }
    A += b2[0]; Bv += b2[1];
    float mx = fmaxf(A, Bv);
    float e0 = __expf(A - mx), e1 = __expf(Bv - mx);
    float inv = 1.f / (e0 + e1);
    g[b * 2] = e0 * inv;
    g[b * 2 + 1] = e1 * inv;
  }
}

// combined = g0*local_norm + g1*comp  (bf16 out)
__global__ __launch_bounds__(256) void combine_k(const float* __restrict__ ln,
                                                 const float* __restrict__ comp,
                                                 const float* __restrict__ g,
                                                 u16* __restrict__ out) {
  size_t i = (size_t)blockIdx.x * 256 + threadIdx.x;
  size_t off = i << 2;
  int b = (int)(off >> 20);
  float g0 = g[b * 2], g1 = g[b * 2 + 1];
  f32x4 a = *(const f32x4*)(ln + off);
  f32x4 c = *(const f32x4*)(comp + off);
  u16x4 o = {f2bf(g0 * a[0] + g1 * c[0]), f2bf(g0 * a[1] + g1 * c[1]),
             f2bf(g0 * a[2] + g1 * c[2]), f2bf(g0 * a[3] + g1 * c[3])};
  *(u16x4*)(out + off) = o;
}

// ---------------- host launch ----------------
extern "C" void kernel_launch(void* const* d_in, const int* in_sizes, int n_in,
                              void* d_out, int out_size, void* d_ws, size_t ws_size,
                              hipStream_t stream) {
  const float* x        = (const float*)d_in[0];
  const float* c_attn_w = (const float*)d_in[1];
  const float* c_attn_b = (const float*)d_in[2];
  const float* c_proj_w = (const float*)d_in[3];
  const float* c_proj_b = (const float*)d_in[4];
  const float* conv_w   = (const float*)d_in[5];
  const float* conv_b   = (const float*)d_in[6];
  const float* comp_ln_w= (const float*)d_in[7];
  const float* comp_ln_b= (const float*)d_in[8];
  const float* ln_loc_w = (const float*)d_in[9];
  const float* ln_loc_b = (const float*)d_in[10];
  const float* gate_w1  = (const float*)d_in[11];
  const float* gate_b1  = (const float*)d_in[12];
  const float* gate_ln_w= (const float*)d_in[13];
  const float* gate_ln_b= (const float*)d_in[14];
  const float* gate_w2  = (const float*)d_in[15];
  const float* gate_b2  = (const float*)d_in[16];
  float* out = (float*)d_out;

  char* ws = (char*)d_ws;
  size_t off = 0;
  auto alloc = [&](size_t bytes) -> char* {
    char* p = ws + off;
    off += (bytes + 255) & ~(size_t)255;
    return p;
  };
  u16* x_bf     = (u16*)alloc(8388608);   // reused as `combined` after QKV GEMM
  u16* attn_wT  = (u16*)alloc(6291456);
  u16* proj_wT  = (u16*)alloc(2097152);
  u16* wfrag    = (u16*)alloc(262144);    // 64 ic x 4 j x 64 lanes x 8 elems bf16
  u16* q_bf     = (u16*)alloc(8388608);
  u16* k_bf     = (u16*)alloc(8388608);
  u16* kT_bf    = (u16*)alloc(8388608);
  u16* vT_bf    = (u16*)alloc(8388608);
  u16* k_comp   = (u16*)alloc(524288);
  u16* v_compT  = (u16*)alloc(524288);
  float* local  = (float*)alloc(16777216);
  float* comp   = (float*)alloc(16777216);
  float* partial= (float*)alloc(1048576);
  float* gbuf   = (float*)alloc(256);
  u16* combined = x_bf;  // x_bf dead after gemm_qkv
  if (off > ws_size) return;

  // 1. casts / transposes
  cast_bf16<<<dim3(4096), dim3(256), 0, stream>>>(x, x_bf, 1048576);
  transpose_cast<<<dim3(96, 32), dim3(256), 0, stream>>>(c_attn_w, attn_wT, 1024, 3072);
  transpose_cast<<<dim3(32, 32), dim3(256), 0, stream>>>(c_proj_w, proj_wT, 1024, 1024);
  cast_wfrag<<<dim3(64), dim3(256), 0, stream>>>(conv_w, wfrag);

  // 2. QKV GEMM + scatter
  gemm_qkv<<<dim3(32, 24), dim3(256), 0, stream>>>(x_bf, attn_wT, c_attn_b,
                                                   q_bf, k_bf, kT_bf, vT_bf);

  // 3. conv compression (k and v), 8-wave blocks, fragment-ordered weights
  conv_comp<<<dim3(64, 2), dim3(512), 0, stream>>>(kT_bf, vT_bf, wfrag, conv_b,
                                                   comp_ln_w, comp_ln_b, k_comp, v_compT);

  // 4. local causal flash attention (K staged, V reg-prefetched, XCD-pinned)
  flash64<<<dim3(1024), dim3(256), 0, stream>>>(q_bf, k_bf, vT_bf, local,
                                                65536, 65536, 1024, 1024);
  // 5. compressed attention (1 KV tile)
  flash64<<<dim3(1024), dim3(256), 0, stream>>>(q_bf, k_comp, v_compT, comp,
                                                4096, 4096, 64, 63);

  // 6. LN(local) in place
  ln_rows<<<dim3(4096), dim3(256), 0, stream>>>(local, ln_loc_w, ln_loc_b);

  // 7. gate MLP
  gate_partial<<<dim3(64), dim3(256), 0, stream>>>(local, comp, gate_w1, partial);
  gate_finish<<<dim3(4), dim3(1024), 0, stream>>>(partial, gate_b1, gate_ln_w,
                                                  gate_ln_b, gate_w2, gate_b2, gbuf);

  // 8. combine + output projection
  combine_k<<<dim3(4096), dim3(256), 0, stream>>>(local, comp, gbuf, combined);
  gemm_proj<<<dim3(32, 8), dim3(256), 0, stream>>>(combined, proj_wT, c_proj_b, out);
}